// Round 13
// baseline (95.459 us; speedup 1.0000x reference)
//
#include <hip/hip_runtime.h>
#include <math.h>

#define NB    32768
#define DDIM  64
#define HDIM  512
#define PDIM  23        // 3*K - 1
#define KBINS 8
#define BM    32
#define NCOLS (DDIM * PDIM)   // 1472
#define CH2   184             // cols per chunk = 8 d's
#define NCH   8               // chunks
#define TPC   12              // tile-slots per chunk (11 full + 1 straddle @168)
#define PSTR2 185             // f32 stride per pstage row (odd -> conflict-free reads)
#define PBUFH (BM * PSTR2)    // 5920 floats per buffer

#define RQ_BOUND  4.0f
#define RQ_MINBIN 0.001f
#define RQ_MINDER 0.001f

typedef __attribute__((ext_vector_type(8))) _Float16 half8;
typedef __attribute__((ext_vector_type(4))) float f32x4;
typedef unsigned short ushort_t;

// ---------------------------------------------------------------------------
// prep: masks + fp16 + fragment-major. W1g unchanged (validated R10).
// W2g now has 96 tile-slots: slot tt = c*12 + i, col base = c*184 + (i<11 ? i*16 : 168)
// (straddle tile duplicates 8 cols; 4% extra storage). Element order within a
// slot: [kt 0..15][lane 0..63][8 elems] -> every B-frag load is 1KB coalesced.
// masks: M1[h,i] = i <= h%63 ; M2[o,h] = o/23 > h%63
// ---------------------------------------------------------------------------
__global__ __launch_bounds__(256) void prep_frag(const float* __restrict__ W1,
                                                 const float* __restrict__ W2,
                                                 _Float16* __restrict__ W1g,
                                                 _Float16* __restrict__ W2g) {
    const int gid = blockIdx.x * 256 + threadIdx.x;
    const int NW1 = 32 * 2 * 64;            // 4096 fragment-groups for W1
    if (gid < NW1) {
        const int lane = gid & 63;
        const int tk   = gid >> 6;          // htile*2 + kt
        const int kt   = tk & 1, ht = tk >> 1;
        const int h = ht * 16 + (lane & 15);
        const int k = kt * 32 + (lane >> 4) * 8;
        const float* src = W1 + h * DDIM + k;
        const int hm63 = h % 63;
        half8 v;
        #pragma unroll
        for (int e = 0; e < 8; ++e)
            v[e] = (_Float16)(((k + e) <= hm63) ? src[e] : 0.0f);
        *(half8*)(W1g + (size_t)gid * 8) = v;
    } else {
        const int g2 = gid - NW1;
        if (g2 < 96 * 16 * 64) {
            const int lane = g2 & 63;
            const int tk   = g2 >> 6;       // tt*16 + kt
            const int kt   = tk & 15, tt = tk >> 4;
            const int c    = tt / TPC;
            const int i    = tt - c * TPC;
            const int colbase = c * CH2 + (i < 11 ? i * 16 : 168);
            const int col  = colbase + (lane & 15);
            const int k    = kt * 32 + (lane >> 4) * 8;
            const float* src = W2 + (size_t)col * HDIM + k;
            const int d = col / PDIM;
            half8 v;
            #pragma unroll
            for (int e = 0; e < 8; ++e)
                v[e] = (_Float16)((d > ((k + e) % 63)) ? src[e] : 0.0f);
            *(half8*)(W2g + (size_t)g2 * 8) = v;
        }
    }
}

// ---------------------------------------------------------------------------
// fast transcendentals (validated round 5)
// ---------------------------------------------------------------------------
__device__ __forceinline__ float fexp(float v)  { return __expf(v); }
__device__ __forceinline__ float flog(float v)  { return __logf(v); }
__device__ __forceinline__ float fdiv(float a, float b) { return __fdividef(a, b); }

// ---------------------------------------------------------------------------
// rational-quadratic spline (R12 trimmed version, validated: absmax 0.875)
// ---------------------------------------------------------------------------
__device__ __forceinline__ void rqs_eval(const float* prm, float xorig,
                                         float& yo, float& ldo) {
    const float xc = fminf(fmaxf(xorig, -RQ_BOUND), RQ_BOUND);
    const bool inside = (xorig >= -RQ_BOUND) && (xorig <= RQ_BOUND);
    const float CNORM = 1.0f - RQ_MINBIN * KBINS;

    float xk[KBINS + 1], yk[KBINS + 1], dd[KBINS + 1];
    {
        float e[KBINS]; float s = 0.0f;
        #pragma unroll
        for (int i = 0; i < KBINS; ++i) { e[i] = fexp(prm[i]); s += e[i]; }
        const float cinv = CNORM * fdiv(1.0f, s);
        float c = 0.0f;
        xk[0] = -RQ_BOUND;
        #pragma unroll
        for (int i = 0; i < KBINS; ++i) {
            c += fmaf(e[i], cinv, RQ_MINBIN);
            xk[i + 1] = fmaf(c, 2.0f * RQ_BOUND, -RQ_BOUND);
        }
        xk[KBINS] = RQ_BOUND;
    }
    {
        float e[KBINS]; float s = 0.0f;
        #pragma unroll
        for (int i = 0; i < KBINS; ++i) { e[i] = fexp(prm[8 + i]); s += e[i]; }
        const float cinv = CNORM * fdiv(1.0f, s);
        float c = 0.0f;
        yk[0] = -RQ_BOUND;
        #pragma unroll
        for (int i = 0; i < KBINS; ++i) {
            c += fmaf(e[i], cinv, RQ_MINBIN);
            yk[i + 1] = fmaf(c, 2.0f * RQ_BOUND, -RQ_BOUND);
        }
        yk[KBINS] = RQ_BOUND;
    }
    dd[0] = 1.0f;
    #pragma unroll
    for (int i = 0; i < KBINS - 1; ++i)
        dd[i + 1] = RQ_MINDER + flog(1.0f + fexp(prm[16 + i]));
    dd[KBINS] = 1.0f;

    int idx = 0;
    #pragma unroll
    for (int i = 1; i < KBINS; ++i) idx += (xc >= xk[i]) ? 1 : 0;

    float x_k = xk[0], x_k1 = xk[1];
    float y_k = yk[0], y_k1 = yk[1];
    float d_k = dd[0], d_k1 = dd[1];
    #pragma unroll
    for (int i = 1; i < KBINS; ++i) {
        const bool mm = (idx == i);
        x_k  = mm ? xk[i]     : x_k;
        x_k1 = mm ? xk[i + 1] : x_k1;
        y_k  = mm ? yk[i]     : y_k;
        y_k1 = mm ? yk[i + 1] : y_k1;
        d_k  = mm ? dd[i]     : d_k;
        d_k1 = mm ? dd[i + 1] : d_k1;
    }

    const float w_k = x_k1 - x_k;
    const float h_k = y_k1 - y_k;
    const float rw  = fdiv(1.0f, w_k);
    const float s   = h_k * rw;
    const float th  = (xc - x_k) * rw;
    const float omt = 1.0f - th;
    const float t1m = th * omt;
    const float num = h_k * (s * th * th + d_k * t1m);
    const float den = s + (d_k1 + d_k - 2.0f * s) * t1m;
    const float yin = y_k + fdiv(num, den);
    const float dnum = s * s * (d_k1 * th * th + 2.0f * s * t1m + d_k * omt * omt);
    const float ldin = flog(fdiv(dnum, den * den));

    yo  = inside ? yin : xorig;
    ldo = inside ? ldin : 0.0f;
}

// ---------------------------------------------------------------------------
// fused kernel, R13: producer/consumer wave specialization.
//   GEMM1: all 8 waves (identical to R12, validated).
//   Phase pipeline (9 phases, 1 barrier each): waves 0-5 produce chunk c
//   (2 tiles each, 16x16x32 MFMA, b2 folded at staging) into pbuf[c&1];
//   waves 6-7 consume chunk c-1 (2 spline evals/thread) from pbuf[(c-1)&1].
//   z buffered in 16 named registers (static indexing), flushed at the end
//   via LDS transpose into full float4 rows. LDS 80128 B -> 2 blocks/CU.
// ---------------------------------------------------------------------------
__global__ __launch_bounds__(512, 4) void fused_flow(
    const float* __restrict__ x,  const float* __restrict__ b1,
    const float* __restrict__ b2, const _Float16* __restrict__ W1g,
    const _Float16* __restrict__ W2g,
    float* __restrict__ z_out, float* __restrict__ ld_out)
{
    __shared__ __align__(16) ushort_t hm[BM * 512];   // 32 KB fp16, swizzled
    __shared__ __align__(16) float pbuf[2 * PBUFH];   // 47360 B (double buffer)

    const int t    = threadIdx.x;
    const int row0 = blockIdx.x * BM;
    const int wv   = t >> 6;
    const int lane = t & 63;
    const int l15  = lane & 15;
    const int lg   = lane >> 4;

    char* hmB = (char*)hm;

    // ---- phase 1: GEMM1 (all 8 waves; identical to R12) ----
    {
        f32x4 acc1[4][2];
        #pragma unroll
        for (int j = 0; j < 4; ++j)
            #pragma unroll
            for (int m = 0; m < 2; ++m) acc1[j][m] = (f32x4){0.f, 0.f, 0.f, 0.f};

        #pragma unroll
        for (int kt = 0; kt < 2; ++kt) {
            half8 a[2];
            #pragma unroll
            for (int m = 0; m < 2; ++m) {
                const float* xr = x + (size_t)(row0 + m * 16 + l15) * DDIM + kt * 32 + lg * 8;
                const float4 xa = *(const float4*)(xr);
                const float4 xb = *(const float4*)(xr + 4);
                a[m][0] = (_Float16)xa.x; a[m][1] = (_Float16)xa.y;
                a[m][2] = (_Float16)xa.z; a[m][3] = (_Float16)xa.w;
                a[m][4] = (_Float16)xb.x; a[m][5] = (_Float16)xb.y;
                a[m][6] = (_Float16)xb.z; a[m][7] = (_Float16)xb.w;
            }
            #pragma unroll
            for (int j = 0; j < 4; ++j) {
                const half8 b = *(const half8*)(W1g + (size_t)(wv * 4 + j) * 1024 + kt * 512 + lane * 8);
                #pragma unroll
                for (int m = 0; m < 2; ++m)
                    acc1[j][m] = __builtin_amdgcn_mfma_f32_16x16x32_f16(a[m], b, acc1[j][m], 0, 0, 0);
            }
        }
        #pragma unroll
        for (int j = 0; j < 4; ++j) {
            const int h = (wv * 4 + j) * 16 + l15;
            const float bias = b1[h];
            #pragma unroll
            for (int m = 0; m < 2; ++m) {
                #pragma unroll
                for (int q = 0; q < 4; ++q) {
                    const int r = m * 16 + lg * 4 + q;
                    const _Float16 hv = (_Float16)fmaxf(acc1[j][m][q] + bias, 0.0f);
                    *(ushort_t*)(hmB + r * 1024 + ((h * 2) ^ ((r & 7) << 4))) =
                        __builtin_bit_cast(ushort_t, hv);
                }
            }
        }
    }
    __syncthreads();

    // ---- phase 2: producer/consumer pipeline ----
    const bool producer = (wv < 6);
    const int  tloc = t - 384;          // consumer-local id (garbage for producers)
    const int  srow = tloc & 31;        // consumer spline row
    const int  dq   = tloc >> 5;        // consumer d-quadrant 0..3 (w6:0-1, w7:2-3)

    // producer W2 bases: slot j = 2wv+i (clamped; only wv<6 dereferences)
    const _Float16* w2base[2];
    #pragma unroll
    for (int i = 0; i < 2; ++i) {
        const int j = (2 * wv + i < TPC) ? (2 * wv + i) : (TPC - 1);
        w2base[i] = W2g + (size_t)j * 8192 + lane * 8;
    }

    float ldacc = 0.0f;
    float z0a, z0b, z1a, z1b, z2a, z2b, z3a, z3b;
    float z4a, z4b, z5a, z5b, z6a, z6b, z7a, z7b;

    auto PROD = [&](int C) {
        f32x4 acc[2][2];
        #pragma unroll
        for (int i = 0; i < 2; ++i)
            #pragma unroll
            for (int m = 0; m < 2; ++m) acc[i][m] = (f32x4){0.f, 0.f, 0.f, 0.f};
        const size_t coff = (size_t)C * (TPC * 8192);
        #pragma unroll 4
        for (int kt = 0; kt < 16; ++kt) {
            half8 ah[2];
            #pragma unroll
            for (int m = 0; m < 2; ++m) {
                const int r  = m * 16 + l15;
                const int kb = (kt * 32 + lg * 8) * 2;
                ah[m] = *(const half8*)(hmB + r * 1024 + (kb ^ ((r & 7) << 4)));
            }
            half8 bfr[2];
            #pragma unroll
            for (int i = 0; i < 2; ++i)
                bfr[i] = *(const half8*)(w2base[i] + coff + kt * 512);   // 1KB coalesced
            #pragma unroll
            for (int i = 0; i < 2; ++i)
                #pragma unroll
                for (int m = 0; m < 2; ++m)
                    acc[i][m] = __builtin_amdgcn_mfma_f32_16x16x32_f16(ah[m], bfr[i], acc[i][m], 0, 0, 0);
        }
        // stage (fold b2 here; straddle tile 11 stages only cols 176..183)
        float* pb = pbuf + (C & 1) * PBUFH;
        #pragma unroll
        for (int i = 0; i < 2; ++i) {
            const int j = 2 * wv + i;
            const int lcol = (j < 11 ? j * 16 : 168) + l15;
            if (j < 11 || l15 >= 8) {
                const float bb = b2[C * CH2 + lcol];
                #pragma unroll
                for (int m = 0; m < 2; ++m)
                    #pragma unroll
                    for (int q = 0; q < 4; ++q)
                        pb[(m * 16 + lg * 4 + q) * PSTR2 + lcol] = acc[i][m][q] + bb;
            }
        }
    };

    auto EVAL = [&](int sc, int dloc, float& zdst) {
        const float* pb = pbuf + (sc & 1) * PBUFH + srow * PSTR2 + dloc * PDIM;
        float prm[PDIM];
        #pragma unroll
        for (int p = 0; p < PDIM; ++p) prm[p] = pb[p];
        const int d = sc * 8 + dloc;
        const float xv = x[(size_t)(row0 + srow) * DDIM + d];
        float yv, lv;
        rqs_eval(prm, xv, yv, lv);
        zdst = yv;
        ldacc += lv;
    };

    #define STEP(C, ZA, ZB)                                             \
        __syncthreads();                                                \
        if (producer) { PROD(C); }                                      \
        else { EVAL(C - 1, dq, ZA); EVAL(C - 1, dq + 4, ZB); }

    __syncthreads();
    if (producer) PROD(0);
    STEP(1, z0a, z0b)
    STEP(2, z1a, z1b)
    STEP(3, z2a, z2b)
    STEP(4, z3a, z3b)
    STEP(5, z4a, z4b)
    STEP(6, z5a, z5b)
    STEP(7, z6a, z6b)
    __syncthreads();
    if (!producer) { EVAL(7, dq, z7a); EVAL(7, dq + 4, z7b); }
    #undef STEP

    // ---- epilogue: z via LDS transpose (coalesced), ld reduce ----
    // consumers scatter to zls[srow*65 + d] in the dead pbuf[0] region
    // (phase 8 readers use pbuf[1]; offsets 0..2143 are free)
    if (!producer) {
        float* zls = pbuf;
        #define ZSC(SC, ZA, ZB)                         \
            zls[srow * 65 + SC * 8 + dq]     = ZA;      \
            zls[srow * 65 + SC * 8 + dq + 4] = ZB;
        ZSC(0, z0a, z0b) ZSC(1, z1a, z1b) ZSC(2, z2a, z2b) ZSC(3, z3a, z3b)
        ZSC(4, z4a, z4b) ZSC(5, z5a, z5b) ZSC(6, z6a, z6b) ZSC(7, z7a, z7b)
        #undef ZSC
        ldacc += __shfl_xor(ldacc, 32, 64);           // combine dq pairs (same srow)
        if (lane < 32) zls[2080 + (wv - 6) * 32 + srow] = ldacc;
    }
    __syncthreads();
    {   // all 512 threads: full float4 rows
        const int r  = t >> 4;
        const int d0 = (t & 15) * 4;
        const float* zls = pbuf;
        float4 zv;
        zv.x = zls[r * 65 + d0 + 0];
        zv.y = zls[r * 65 + d0 + 1];
        zv.z = zls[r * 65 + d0 + 2];
        zv.w = zls[r * 65 + d0 + 3];
        *(float4*)(z_out + (size_t)(row0 + r) * DDIM + d0) = zv;
    }
    if (t < BM) ld_out[row0 + t] = pbuf[2080 + t] + pbuf[2112 + t];
}

// ---------------------------------------------------------------------------
extern "C" void kernel_launch(void* const* d_in, const int* in_sizes, int n_in,
                              void* d_out, int out_size, void* d_ws, size_t ws_size,
                              hipStream_t stream) {
    (void)in_sizes; (void)n_in; (void)out_size; (void)ws_size;
    const float* x  = (const float*)d_in[0];
    const float* W1 = (const float*)d_in[1];
    const float* b1 = (const float*)d_in[2];
    const float* W2 = (const float*)d_in[3];
    const float* b2 = (const float*)d_in[4];

    _Float16* W1g = (_Float16*)d_ws;                 // 32768 fp16 (frag-major)
    _Float16* W2g = W1g + HDIM * DDIM;               // 96*16*512 = 786432 fp16
    float* z  = (float*)d_out;
    float* ld = z + (size_t)NB * DDIM;

    const int n_groups = 32 * 2 * 64 + 96 * 16 * 64;   // 102400 fragment-groups
    prep_frag<<<(n_groups + 255) / 256, 256, 0, stream>>>(W1, W2, W1g, W2g);
    fused_flow<<<NB / BM, 512, 0, stream>>>(x, b1, b2, W1g, W2g, z, ld);
}